// Round 5
// baseline (654.988 us; speedup 1.0000x reference)
//
#include <hip/hip_runtime.h>

typedef unsigned short u16;
typedef unsigned int u32;
typedef __attribute__((ext_vector_type(8))) short short8;   // 8 bf16 = 4 VGPR MFMA operand
typedef __attribute__((ext_vector_type(4))) float f32x4;

#define MFMA(a, b, c) __builtin_amdgcn_mfma_f32_16x16x32_bf16((a), (b), (c), 0, 0, 0)

static __device__ __forceinline__ u16 f2bf(float f) {
  u32 u = __float_as_uint(f);
  u32 r = (u + 0x7FFFu + ((u >> 16) & 1u)) >> 16;   // RNE
  return (u16)r;
}
static __device__ __forceinline__ float bf2f(u16 s) {
  return __uint_as_float(((u32)s) << 16);
}
static __device__ __forceinline__ void gload16(const void* g, void* l) {
  __builtin_amdgcn_global_load_lds(
      (const __attribute__((address_space(1))) void*)g,
      (__attribute__((address_space(3))) void*)l, 16, 0, 0);
}
// swizzled LDS read: rows are 128B; physical col = col ^ ((row&7)<<4)  (T2 st-style swizzle)
static __device__ __forceinline__ short8 lds8(const u16* base, int row, int colb) {
  int phys = row * 128 + (colb ^ ((row & 7) << 4));
  return *(const short8*)((const char*)base + phys);
}

// ---------------- split: fp32 -> bf16 hi/lo ----------------
__global__ void split_kernel(const float* __restrict__ in, u16* __restrict__ hi,
                             u16* __restrict__ lo, int n4) {
  int i = blockIdx.x * blockDim.x + threadIdx.x;
  int stride = gridDim.x * blockDim.x;
  for (; i < n4; i += stride) {
    float4 v = ((const float4*)in)[i];
    ushort4 h, l;
    h.x = f2bf(v.x); l.x = f2bf(v.x - bf2f(h.x));
    h.y = f2bf(v.y); l.y = f2bf(v.y - bf2f(h.y));
    h.z = f2bf(v.z); l.z = f2bf(v.z - bf2f(h.z));
    h.w = f2bf(v.w); l.w = f2bf(v.w - bf2f(h.w));
    ((ushort4*)hi)[i] = h;
    ((ushort4*)lo)[i] = l;
  }
}

// ---------------- QKV projection GEMM ----------------
// C[8192][3072] = X[8192][1024] @ W[3072][1024]^T + b   (NT, hi/lo 3-product for q/k cols)
// Launched 1-D (1536 blocks); bijective XCD swizzle (T1/m204, 1536%8==0) so each XCD
// owns 8 consecutive row-panels (mt) -> A-panel reuse is L2-local.
__global__ __launch_bounds__(256, 2) void gemm_qkv(
    const u16* __restrict__ xh, const u16* __restrict__ xl,
    const u16* __restrict__ wh, const u16* __restrict__ wl,
    const float* __restrict__ bias,
    u16* __restrict__ qfh, u16* __restrict__ qfl,
    u16* __restrict__ kfh, u16* __restrict__ kfl, u16* __restrict__ vfp) {
  __shared__ __align__(16) u16 sAh[128 * 64];
  __shared__ __align__(16) u16 sAl[128 * 64];
  __shared__ __align__(16) u16 sBh[128 * 64];
  __shared__ __align__(16) u16 sBl[128 * 64];
  const int L = blockIdx.x;
  const int swz = (L & 7) * 192 + (L >> 3);   // 1536/8 = 192; bijective
  const int ct = swz % 24, mt = swz / 24;
  const int c0 = ct * 128, m0 = mt * 128;
  const bool isV = (ct >= 16);
  const int tid = threadIdx.x, lane = tid & 63, w = tid >> 6;
  const int wm = w >> 1, wn = w & 1;
  f32x4 acc[4][4] = {};

  for (int t = 0; t < 16; ++t) {
    const int k0 = t * 64;
    for (int j = 0; j < 4; ++j) {
      int chunk = w * 4 + j;
      int r = chunk * 8 + (lane >> 3);
      int cb = (lane & 7) * 16;
      int cbs = cb ^ ((r & 7) << 4);    // inverse-swizzled global source, linear LDS dest
      gload16((const char*)(xh + (size_t)(m0 + r) * 1024 + k0) + cbs, (char*)sAh + chunk * 1024);
      gload16((const char*)(wh + (size_t)(c0 + r) * 1024 + k0) + cbs, (char*)sBh + chunk * 1024);
      if (!isV) {
        gload16((const char*)(xl + (size_t)(m0 + r) * 1024 + k0) + cbs, (char*)sAl + chunk * 1024);
        gload16((const char*)(wl + (size_t)(c0 + r) * 1024 + k0) + cbs, (char*)sBl + chunk * 1024);
      }
    }
    asm volatile("s_waitcnt vmcnt(0)" ::: "memory");
    __syncthreads();

    for (int ki = 0; ki < 2; ++ki) {
      const int colb = (ki * 32 + (lane >> 4) * 8) * 2;
      short8 ah[4], al[4], bh[4], bl[4];
      for (int mi = 0; mi < 4; ++mi) {
        int row = wm * 64 + mi * 16 + (lane & 15);
        ah[mi] = lds8(sAh, row, colb);
        if (!isV) al[mi] = lds8(sAl, row, colb);
      }
      for (int ni = 0; ni < 4; ++ni) {
        int row = wn * 64 + ni * 16 + (lane & 15);
        bh[ni] = lds8(sBh, row, colb);
        if (!isV) bl[ni] = lds8(sBl, row, colb);
      }
      for (int mi = 0; mi < 4; ++mi)
        for (int ni = 0; ni < 4; ++ni) {
          acc[mi][ni] = MFMA(ah[mi], bh[ni], acc[mi][ni]);
          if (!isV) {
            acc[mi][ni] = MFMA(ah[mi], bl[ni], acc[mi][ni]);
            acc[mi][ni] = MFMA(al[mi], bh[ni], acc[mi][ni]);
          }
        }
    }
    __syncthreads();
  }

  // epilogue: bias + fragment-layout stores
  const int g = lane >> 4, cl = lane & 15;
  const int b = m0 >> 11;
  const int n0t = (m0 & 2047) >> 6;
  const int t = n0t + wm;                 // 64-row tile index within the sequence
  if (!isV) {
    for (int ni = 0; ni < 4; ++ni) {
      const int c = c0 + wn * 64 + ni * 16 + cl;
      const float bv = bias[c];
      u16* dh = (c < 1024) ? qfh : kfh;
      u16* dl = (c < 1024) ? qfl : kfl;
      const int p = c & 63, h = (c & 1023) >> 6;
      const int kki = p >> 5, lhi = (p >> 3) & 3, e = p & 7;
      for (int mi = 0; mi < 4; ++mi) {
        // A/B-operand layout: row-in-tile = mi(ni-slot)*16 + lane_lo, elems along p
        size_t base = (((size_t)(b * 16 + h) * 32 + t) * 8 + (size_t)kki * 4 + mi) * 512
                      + (size_t)lhi * 128 + e;
        for (int i = 0; i < 4; ++i) {
          float v = acc[mi][ni][i] + bv;
          u16 h16 = f2bf(v);
          dh[base + (size_t)(g * 4 + i) * 8] = h16;
          dl[base + (size_t)(g * 4 + i) * 8] = f2bf(v - bf2f(h16));
        }
      }
    }
  } else {
    for (int ni = 0; ni < 4; ++ni) {
      const int c = c0 + wn * 64 + ni * 16 + cl;
      const float bv = bias[c];
      const int cv = c - 2048, h = cv >> 6, p = cv & 63;
      const int niv = p >> 4, lane_lo = p & 15;
      for (int mi = 0; mi < 4; ++mi) {
        const int kki = mi >> 1;
        for (int i = 0; i < 4; ++i) {
          // B-operand layout for PV: row = p, elems along kv
          const int lhi = (mi & 1) * 2 + (g >> 1);
          const int e = (g & 1) * 4 + i;
          size_t a = (((size_t)(b * 16 + h) * 32 + t) * 8 + (size_t)kki * 4 + niv) * 512
                     + (size_t)(lhi * 16 + lane_lo) * 8 + e;
          vfp[a] = f2bf(acc[mi][ni][i] + bv);
        }
      }
    }
  }
}

// ---------------- flash attention (barrier-free, XCD-colocated, high-TLP) ----------------
// 2048 blocks 1-D, 4 waves/block, 16 q-rows per wave (64-row q tile per block).
// Decode keeps all 32 q-blocks of a bh on ONE XCD: xcd=bid&7, bh=xcd*8+(li>>5), qt=li&31.
// No __syncthreads; only per-wave pbuf LDS. Occupancy target 6-8 waves/SIMD.
__global__ __launch_bounds__(256, 6) void attn_kernel(
    const u16* __restrict__ qfh, const u16* __restrict__ qfl,
    const u16* __restrict__ kfh, const u16* __restrict__ kfl,
    const u16* __restrict__ vfp, float* __restrict__ out) {
  __shared__ __align__(16) u16 pbuf[4][16 * 72];

  const int tid = threadIdx.x, lane = tid & 63, w = tid >> 6;
  const int bid = blockIdx.x;
  const int xcd = bid & 7, li = bid >> 3;
  const int bh = xcd * 8 + (li >> 5);
  const int qt = li & 31;                          // 64-row tile index (writer's t)
  const size_t bhbase = (size_t)bh * 32 * 4096;    // per t: 2ki*4ni*512 = 4096 u16

  // Q fragments (hi/lo): tile qt, mi-slot = wave id
  short8 qhf[2], qlf[2];
  for (int ki = 0; ki < 2; ++ki) {
    size_t a = bhbase + (((size_t)qt * 2 + ki) * 4 + w) * 512 + (size_t)lane * 8;
    qhf[ki] = *(const short8*)(qfh + a);
    qlf[ki] = *(const short8*)(qfl + a);
  }

  f32x4 oacc[4] = {};
  float mrow[4], lrow[4];
  for (int i = 0; i < 4; ++i) { mrow[i] = -3.0e38f; lrow[i] = 0.f; }

  for (int t = 0; t < 32; ++t) {
    const size_t tb = bhbase + (size_t)t * 4096;

    // S = Q K^T  (3-product hi/lo), K fragments direct from global (L2-resident)
    f32x4 sacc[4] = {};
    for (int ki = 0; ki < 2; ++ki) {
      short8 khf[4], klf[4];
      for (int ni = 0; ni < 4; ++ni) {
        size_t a = tb + (((size_t)ki * 4 + ni) * 64 + lane) * 8;
        khf[ni] = *(const short8*)(kfh + a);
        klf[ni] = *(const short8*)(kfl + a);
      }
      for (int ni = 0; ni < 4; ++ni) {
        sacc[ni] = MFMA(qhf[ki], khf[ni], sacc[ni]);
        sacc[ni] = MFMA(qhf[ki], klf[ni], sacc[ni]);
        sacc[ni] = MFMA(qlf[ki], khf[ni], sacc[ni]);
      }
    }

    // online softmax (16 rows spread over 16-lane groups; 4 rows per lane)
    for (int i = 0; i < 4; ++i) {
      float mx = fmaxf(fmaxf(sacc[0][i], sacc[1][i]), fmaxf(sacc[2][i], sacc[3][i]));
      mx = fmaxf(mx, __shfl_xor(mx, 1));
      mx = fmaxf(mx, __shfl_xor(mx, 2));
      mx = fmaxf(mx, __shfl_xor(mx, 4));
      mx = fmaxf(mx, __shfl_xor(mx, 8));
      float mnew = fmaxf(mrow[i], mx);
      float corr = __expf(mrow[i] - mnew);
      mrow[i] = mnew;
      float rs = 0.f;
      int prow = (lane >> 4) * 4 + i;
      for (int ni = 0; ni < 4; ++ni) {
        float p = __expf(sacc[ni][i] - mnew);
        rs += p;
        pbuf[w][prow * 72 + ni * 16 + (lane & 15)] =
            (u16)((__float_as_uint(p) + 0x8000u) >> 16);   // cheap nearest
      }
      rs += __shfl_xor(rs, 1);
      rs += __shfl_xor(rs, 2);
      rs += __shfl_xor(rs, 4);
      rs += __shfl_xor(rs, 8);
      lrow[i] = lrow[i] * corr + rs;
      for (int ni = 0; ni < 4; ++ni) oacc[ni][i] *= corr;
    }

    // O += P V  (P transposed through per-wave LDS; V consumed straight from global)
    for (int ki = 0; ki < 2; ++ki) {
      const int cp = ki * 32 + (lane >> 4) * 8;
      short8 pf = *(const short8*)&pbuf[w][(lane & 15) * 72 + cp];
      for (int ni = 0; ni < 4; ++ni) {
        short8 vf = *(const short8*)(vfp + tb + (((size_t)ki * 4 + ni) * 64 + lane) * 8);
        oacc[ni] = MFMA(pf, vf, oacc[ni]);
      }
    }
  }

  // epilogue: O / l  -> out in faithful (B,H,N,pd) flat layout, fp32
  for (int i = 0; i < 4; ++i) {
    float inv = 1.f / lrow[i];
    int grow = qt * 64 + w * 16 + (lane >> 4) * 4 + i;
    size_t obase = ((size_t)bh * 2048 + grow) * 64;
    for (int ni = 0; ni < 4; ++ni)
      out[obase + ni * 16 + (lane & 15)] = oacc[ni][i] * inv;
  }
}

extern "C" void kernel_launch(void* const* d_in, const int* in_sizes, int n_in,
                              void* d_out, int out_size, void* d_ws, size_t ws_size,
                              hipStream_t stream) {
  (void)in_sizes; (void)n_in; (void)out_size; (void)ws_size;
  const float* x = (const float*)d_in[0];
  const float* Wqkv = (const float*)d_in[1];
  const float* bqkv = (const float*)d_in[2];
  float* out = (float*)d_out;

  u16* xh  = (u16*)d_ws;                 // [8192][1024]
  u16* xl  = xh + 8388608;
  u16* wh  = xl + 8388608;               // [3072][1024]
  u16* wl  = wh + 3145728;
  u16* qfh = wl + 3145728;               // fragment layouts: [bh][t][ki][ni][lane][8]
  u16* qfl = qfh + 8388608;
  u16* kfh = qfl + 8388608;
  u16* kfl = kfh + 8388608;
  u16* vfp = kfl + 8388608;
  // total ws use: 130 MB (same as passing R1 layout)

  split_kernel<<<2048, 256, 0, stream>>>(x, xh, xl, 8388608 / 4);
  split_kernel<<<768, 256, 0, stream>>>(Wqkv, wh, wl, 3145728 / 4);
  gemm_qkv<<<1536, 256, 0, stream>>>(xh, xl, wh, wl, bqkv, qfh, qfl, kfh, kfl, vfp);
  attn_kernel<<<2048, 256, 0, stream>>>(qfh, qfl, kfh, kfl, vfp, out);
}

// Round 6
// 405.047 us; speedup vs baseline: 1.6171x; 1.6171x over previous
//
#include <hip/hip_runtime.h>

typedef unsigned short u16;
typedef unsigned int u32;
typedef __attribute__((ext_vector_type(8))) short short8;   // 8 bf16 = 4 VGPR MFMA operand
typedef __attribute__((ext_vector_type(4))) float f32x4;

#define MFMA(a, b, c) __builtin_amdgcn_mfma_f32_16x16x32_bf16((a), (b), (c), 0, 0, 0)

static __device__ __forceinline__ u16 f2bf(float f) {
  u32 u = __float_as_uint(f);
  u32 r = (u + 0x7FFFu + ((u >> 16) & 1u)) >> 16;   // RNE
  return (u16)r;
}
static __device__ __forceinline__ float bf2f(u16 s) {
  return __uint_as_float(((u32)s) << 16);
}
static __device__ __forceinline__ void gload16(const void* g, void* l) {
  __builtin_amdgcn_global_load_lds(
      (const __attribute__((address_space(1))) void*)g,
      (__attribute__((address_space(3))) void*)l, 16, 0, 0);
}
// swizzled LDS read: rows are 128B; physical col = col ^ ((row&7)<<4)  (T2 st-style swizzle)
static __device__ __forceinline__ short8 lds8(const u16* base, int row, int colb) {
  int phys = row * 128 + (colb ^ ((row & 7) << 4));
  return *(const short8*)((const char*)base + phys);
}

// ---------------- split: fp32 -> bf16 hi/lo ----------------
__global__ void split_kernel(const float* __restrict__ in, u16* __restrict__ hi,
                             u16* __restrict__ lo, int n4) {
  int i = blockIdx.x * blockDim.x + threadIdx.x;
  int stride = gridDim.x * blockDim.x;
  for (; i < n4; i += stride) {
    float4 v = ((const float4*)in)[i];
    ushort4 h, l;
    h.x = f2bf(v.x); l.x = f2bf(v.x - bf2f(h.x));
    h.y = f2bf(v.y); l.y = f2bf(v.y - bf2f(h.y));
    h.z = f2bf(v.z); l.z = f2bf(v.z - bf2f(h.z));
    h.w = f2bf(v.w); l.w = f2bf(v.w - bf2f(h.w));
    ((ushort4*)hi)[i] = h;
    ((ushort4*)lo)[i] = l;
  }
}

// ---------------- QKV projection GEMM (unchanged from R4) ----------------
__global__ __launch_bounds__(256, 2) void gemm_qkv(
    const u16* __restrict__ xh, const u16* __restrict__ xl,
    const u16* __restrict__ wh, const u16* __restrict__ wl,
    const float* __restrict__ bias,
    u16* __restrict__ qfh, u16* __restrict__ qfl,
    u16* __restrict__ kfh, u16* __restrict__ kfl, u16* __restrict__ vfp) {
  __shared__ __align__(16) u16 sAh[128 * 64];
  __shared__ __align__(16) u16 sAl[128 * 64];
  __shared__ __align__(16) u16 sBh[128 * 64];
  __shared__ __align__(16) u16 sBl[128 * 64];
  const int L = blockIdx.x;
  const int swz = (L & 7) * 192 + (L >> 3);   // 1536/8 = 192; bijective
  const int ct = swz % 24, mt = swz / 24;
  const int c0 = ct * 128, m0 = mt * 128;
  const bool isV = (ct >= 16);
  const int tid = threadIdx.x, lane = tid & 63, w = tid >> 6;
  const int wm = w >> 1, wn = w & 1;
  f32x4 acc[4][4] = {};

  for (int t = 0; t < 16; ++t) {
    const int k0 = t * 64;
    for (int j = 0; j < 4; ++j) {
      int chunk = w * 4 + j;
      int r = chunk * 8 + (lane >> 3);
      int cb = (lane & 7) * 16;
      int cbs = cb ^ ((r & 7) << 4);    // inverse-swizzled global source, linear LDS dest
      gload16((const char*)(xh + (size_t)(m0 + r) * 1024 + k0) + cbs, (char*)sAh + chunk * 1024);
      gload16((const char*)(wh + (size_t)(c0 + r) * 1024 + k0) + cbs, (char*)sBh + chunk * 1024);
      if (!isV) {
        gload16((const char*)(xl + (size_t)(m0 + r) * 1024 + k0) + cbs, (char*)sAl + chunk * 1024);
        gload16((const char*)(wl + (size_t)(c0 + r) * 1024 + k0) + cbs, (char*)sBl + chunk * 1024);
      }
    }
    asm volatile("s_waitcnt vmcnt(0)" ::: "memory");
    __syncthreads();

    for (int ki = 0; ki < 2; ++ki) {
      const int colb = (ki * 32 + (lane >> 4) * 8) * 2;
      short8 ah[4], al[4], bh[4], bl[4];
      for (int mi = 0; mi < 4; ++mi) {
        int row = wm * 64 + mi * 16 + (lane & 15);
        ah[mi] = lds8(sAh, row, colb);
        if (!isV) al[mi] = lds8(sAl, row, colb);
      }
      for (int ni = 0; ni < 4; ++ni) {
        int row = wn * 64 + ni * 16 + (lane & 15);
        bh[ni] = lds8(sBh, row, colb);
        if (!isV) bl[ni] = lds8(sBl, row, colb);
      }
      for (int mi = 0; mi < 4; ++mi)
        for (int ni = 0; ni < 4; ++ni) {
          acc[mi][ni] = MFMA(ah[mi], bh[ni], acc[mi][ni]);
          if (!isV) {
            acc[mi][ni] = MFMA(ah[mi], bl[ni], acc[mi][ni]);
            acc[mi][ni] = MFMA(al[mi], bh[ni], acc[mi][ni]);
          }
        }
    }
    __syncthreads();
  }

  // epilogue: bias + fragment-layout stores
  const int g = lane >> 4, cl = lane & 15;
  const int b = m0 >> 11;
  const int n0t = (m0 & 2047) >> 6;
  const int t = n0t + wm;                 // 64-row tile index within the sequence
  if (!isV) {
    for (int ni = 0; ni < 4; ++ni) {
      const int c = c0 + wn * 64 + ni * 16 + cl;
      const float bv = bias[c];
      u16* dh = (c < 1024) ? qfh : kfh;
      u16* dl = (c < 1024) ? qfl : kfl;
      const int p = c & 63, h = (c & 1023) >> 6;
      const int kki = p >> 5, lhi = (p >> 3) & 3, e = p & 7;
      for (int mi = 0; mi < 4; ++mi) {
        size_t base = (((size_t)(b * 16 + h) * 32 + t) * 8 + (size_t)kki * 4 + mi) * 512
                      + (size_t)lhi * 128 + e;
        for (int i = 0; i < 4; ++i) {
          float v = acc[mi][ni][i] + bv;
          u16 h16 = f2bf(v);
          dh[base + (size_t)(g * 4 + i) * 8] = h16;
          dl[base + (size_t)(g * 4 + i) * 8] = f2bf(v - bf2f(h16));
        }
      }
    }
  } else {
    for (int ni = 0; ni < 4; ++ni) {
      const int c = c0 + wn * 64 + ni * 16 + cl;
      const float bv = bias[c];
      const int cv = c - 2048, h = cv >> 6, p = cv & 63;
      const int niv = p >> 4, lane_lo = p & 15;
      for (int mi = 0; mi < 4; ++mi) {
        const int kki = mi >> 1;
        for (int i = 0; i < 4; ++i) {
          const int lhi = (mi & 1) * 2 + (g >> 1);
          const int e = (g & 1) * 4 + i;
          size_t a = (((size_t)(b * 16 + h) * 32 + t) * 8 + (size_t)kki * 4 + niv) * 512
                     + (size_t)(lhi * 16 + lane_lo) * 8 + e;
          vfp[a] = f2bf(acc[mi][ni][i] + bv);
        }
      }
    }
  }
}

// ---------------- flash attention (swapped-operand softmax) ----------------
// Grid 1024 (R4 decode): xcd=bid&7, bh=xcd*8+(li>>4), qt=li&15; 4 waves x 32 q-rows.
// Swapped QK^T: S^T = K.Q^T -> col = q = lane&15, row = kv. Row softmax needs only
// in-register trees + 2 shfls (xor 16/32) instead of 4-deep shfl ladders per row.
// PV also swapped: O^T = V^T.P^T (vfp fragment = A directly; P via per-wave pbuf).
__global__ __launch_bounds__(256, 4) void attn_kernel(
    const u16* __restrict__ qfh, const u16* __restrict__ qfl,
    const u16* __restrict__ kfh, const u16* __restrict__ kfl,
    const u16* __restrict__ vfp, float* __restrict__ out) {
  __shared__ __align__(16) u16 pbuf[4][32 * 72];

  const int tid = threadIdx.x, lane = tid & 63, w = tid >> 6;
  const int bid = blockIdx.x;
  const int xcd = bid & 7, li = bid >> 3;
  const int bh = xcd * 8 + (li >> 4);
  const int qt = li & 15;
  const int g = lane >> 4, q = lane & 15;
  const size_t bhbase = (size_t)bh * 32 * 4096;   // per t: 2ki*4ni*512 = 4096 u16

  // Q fragments (hi/lo) — used as B-operand now (same per-lane layout as A)
  short8 qhf[2][2], qlf[2][2];
  for (int mi = 0; mi < 2; ++mi) {
    int idx = 2 * w + mi;
    int t = qt * 2 + (idx >> 2), nni = idx & 3;
    for (int ki = 0; ki < 2; ++ki) {
      size_t a = bhbase + (((size_t)t * 2 + ki) * 4 + nni) * 512 + (size_t)lane * 8;
      qhf[mi][ki] = *(const short8*)(qfh + a);
      qlf[mi][ki] = *(const short8*)(qfl + a);
    }
  }

  f32x4 oaccT[2][4] = {};                 // [mi][d-block]: col=q, row=d
  float mrow[2], lrow[2];
  for (int mi = 0; mi < 2; ++mi) { mrow[mi] = -3.0e38f; lrow[mi] = 0.f; }

  for (int t = 0; t < 32; ++t) {
    const size_t tb = bhbase + (size_t)t * 4096;

    // S^T = K Q^T  (3-product hi/lo); K fragments as A-operand
    f32x4 sacc[2][4] = {};                // [mi][kv-block]: col=q, row=kv
    for (int ki = 0; ki < 2; ++ki) {
      short8 khf[4], klf[4];
      for (int ni = 0; ni < 4; ++ni) {
        size_t a = tb + (((size_t)ki * 4 + ni) * 64 + lane) * 8;
        khf[ni] = *(const short8*)(kfh + a);
        klf[ni] = *(const short8*)(kfl + a);
      }
      for (int mi = 0; mi < 2; ++mi)
        for (int ni = 0; ni < 4; ++ni) {
          sacc[mi][ni] = MFMA(khf[ni], qhf[mi][ki], sacc[mi][ni]);
          sacc[mi][ni] = MFMA(klf[ni], qhf[mi][ki], sacc[mi][ni]);
          sacc[mi][ni] = MFMA(khf[ni], qlf[mi][ki], sacc[mi][ni]);
        }
    }

    // issue V fragment loads; latency hides under softmax
    short8 vfr[2][4];
    for (int ki = 0; ki < 2; ++ki)
      for (int ni = 0; ni < 4; ++ni)
        vfr[ki][ni] = *(const short8*)(vfp + tb + (((size_t)ki * 4 + ni) * 64 + lane) * 8);

    // softmax: per mi, each lane owns q=lane&15; 16 kv values in-register
    for (int mi = 0; mi < 2; ++mi) {
      // max tree over 16 regs
      float a0 = fmaxf(fmaxf(sacc[mi][0][0], sacc[mi][0][1]), fmaxf(sacc[mi][0][2], sacc[mi][0][3]));
      float a1 = fmaxf(fmaxf(sacc[mi][1][0], sacc[mi][1][1]), fmaxf(sacc[mi][1][2], sacc[mi][1][3]));
      float a2 = fmaxf(fmaxf(sacc[mi][2][0], sacc[mi][2][1]), fmaxf(sacc[mi][2][2], sacc[mi][2][3]));
      float a3 = fmaxf(fmaxf(sacc[mi][3][0], sacc[mi][3][1]), fmaxf(sacc[mi][3][2], sacc[mi][3][3]));
      float mx = fmaxf(fmaxf(a0, a1), fmaxf(a2, a3));
      mx = fmaxf(mx, __shfl_xor(mx, 16));
      mx = fmaxf(mx, __shfl_xor(mx, 32));
      float mnew = fmaxf(mrow[mi], mx);
      float corr = __expf(mrow[mi] - mnew);
      mrow[mi] = mnew;
      float rs = 0.f;
      const int prow = mi * 16 + q;
      for (int ni = 0; ni < 4; ++ni) {
        float p0 = __expf(sacc[mi][ni][0] - mnew);
        float p1 = __expf(sacc[mi][ni][1] - mnew);
        float p2 = __expf(sacc[mi][ni][2] - mnew);
        float p3 = __expf(sacc[mi][ni][3] - mnew);
        rs += (p0 + p1) + (p2 + p3);
        ushort4 pk;
        pk.x = (u16)((__float_as_uint(p0) + 0x8000u) >> 16);
        pk.y = (u16)((__float_as_uint(p1) + 0x8000u) >> 16);
        pk.z = (u16)((__float_as_uint(p2) + 0x8000u) >> 16);
        pk.w = (u16)((__float_as_uint(p3) + 0x8000u) >> 16);
        *(ushort4*)&pbuf[w][prow * 72 + ni * 16 + g * 4] = pk;
      }
      rs += __shfl_xor(rs, 16);
      rs += __shfl_xor(rs, 32);
      lrow[mi] = lrow[mi] * corr + rs;
      for (int ni = 0; ni < 4; ++ni)
        for (int i = 0; i < 4; ++i) oaccT[mi][ni][i] *= corr;
    }

    // O^T += V^T P^T  (A = vfp fragment rows=d; B = P rows=q from pbuf)
    for (int ki = 0; ki < 2; ++ki) {
      short8 pf[2];
      for (int mi = 0; mi < 2; ++mi)
        pf[mi] = *(const short8*)&pbuf[w][(mi * 16 + q) * 72 + ki * 32 + g * 8];
      for (int ni = 0; ni < 4; ++ni)
        for (int mi = 0; mi < 2; ++mi)
          oaccT[mi][ni] = MFMA(vfr[ki][ni], pf[mi], oaccT[mi][ni]);
    }
  }

  // epilogue: O^T/l -> out (faithful (B,H,N,pd) flat, fp32). col=q, row=d.
  for (int mi = 0; mi < 2; ++mi) {
    float inv = 1.f / lrow[mi];
    int grow = qt * 128 + w * 32 + mi * 16 + q;
    size_t obase = ((size_t)bh * 2048 + grow) * 64;
    for (int ni = 0; ni < 4; ++ni)
      for (int i = 0; i < 4; ++i)
        out[obase + ni * 16 + g * 4 + i] = oaccT[mi][ni][i] * inv;
  }
}

extern "C" void kernel_launch(void* const* d_in, const int* in_sizes, int n_in,
                              void* d_out, int out_size, void* d_ws, size_t ws_size,
                              hipStream_t stream) {
  (void)in_sizes; (void)n_in; (void)out_size; (void)ws_size;
  const float* x = (const float*)d_in[0];
  const float* Wqkv = (const float*)d_in[1];
  const float* bqkv = (const float*)d_in[2];
  float* out = (float*)d_out;

  u16* xh  = (u16*)d_ws;                 // [8192][1024]
  u16* xl  = xh + 8388608;
  u16* wh  = xl + 8388608;               // [3072][1024]
  u16* wl  = wh + 3145728;
  u16* qfh = wl + 3145728;               // fragment layouts: [bh][t][ki][ni][lane][8]
  u16* qfl = qfh + 8388608;
  u16* kfh = qfl + 8388608;
  u16* kfl = kfh + 8388608;
  u16* vfp = kfl + 8388608;
  // total ws use: 130 MB

  split_kernel<<<2048, 256, 0, stream>>>(x, xh, xl, 8388608 / 4);
  split_kernel<<<768, 256, 0, stream>>>(Wqkv, wh, wl, 3145728 / 4);
  gemm_qkv<<<1536, 256, 0, stream>>>(xh, xl, wh, wl, bqkv, qfh, qfl, kfh, kfl, vfp);
  attn_kernel<<<1024, 256, 0, stream>>>(qfh, qfl, kfh, kfl, vfp, out);
}

// Round 7
// 254.397 us; speedup vs baseline: 2.5747x; 1.5922x over previous
//
#include <hip/hip_runtime.h>

typedef unsigned short u16;
typedef unsigned int u32;
typedef _Float16 f16;
typedef __attribute__((ext_vector_type(8))) f16 half8;   // 8 fp16 = 4 VGPR MFMA operand
typedef __attribute__((ext_vector_type(4))) f16 half4;
typedef __attribute__((ext_vector_type(4))) float f32x4;

#define MFMA16(a, b, c) __builtin_amdgcn_mfma_f32_16x16x32_f16((a), (b), (c), 0, 0, 0)

static __device__ __forceinline__ void gload16(const void* g, void* l) {
  __builtin_amdgcn_global_load_lds(
      (const __attribute__((address_space(1))) void*)g,
      (__attribute__((address_space(3))) void*)l, 16, 0, 0);
}
// swizzled LDS read: rows are 128B; physical col = col ^ ((row&7)<<4)  (T2 st-style swizzle)
static __device__ __forceinline__ half8 lds8h(const f16* base, int row, int colb) {
  int phys = row * 128 + (colb ^ ((row & 7) << 4));
  return *(const half8*)((const char*)base + phys);
}

// ---------------- convert: fp32 -> fp16 (single; products exact in fp32 accum) ----------------
__global__ void cvt_kernel(const float* __restrict__ in, f16* __restrict__ o, int n4) {
  int i = blockIdx.x * blockDim.x + threadIdx.x;
  int stride = gridDim.x * blockDim.x;
  for (; i < n4; i += stride) {
    float4 v = ((const float4*)in)[i];
    half4 h;
    h.x = (f16)v.x; h.y = (f16)v.y; h.z = (f16)v.z; h.w = (f16)v.w;
    *(half4*)(o + (size_t)i * 4) = h;
  }
}

// ---------------- QKV projection GEMM (fp16 single-product, m97 structure) ----------------
// C[8192][3072] = X[8192][1024] @ W[3072][1024]^T + b
// Epilogue writes Q/K/V in MFMA-fragment layout [bh][t(32)][ki(2)][ni(4)][lane(64)][e(8)].
// 1536 blocks, bijective XCD swizzle.
__global__ __launch_bounds__(256, 2) void gemm_qkv(
    const f16* __restrict__ xf, const f16* __restrict__ wf,
    const float* __restrict__ bias,
    f16* __restrict__ qf, f16* __restrict__ kf, f16* __restrict__ vf) {
  __shared__ __align__(16) f16 sA[128 * 64];
  __shared__ __align__(16) f16 sB[128 * 64];
  const int L = blockIdx.x;
  const int swz = (L & 7) * 192 + (L >> 3);   // 1536/8 = 192; bijective
  const int ct = swz % 24, mt = swz / 24;
  const int c0 = ct * 128, m0 = mt * 128;
  const int tid = threadIdx.x, lane = tid & 63, w = tid >> 6;
  const int wm = w >> 1, wn = w & 1;
  f32x4 acc[4][4] = {};

  for (int t = 0; t < 16; ++t) {
    const int k0 = t * 64;
    for (int j = 0; j < 4; ++j) {
      int chunk = w * 4 + j;
      int r = chunk * 8 + (lane >> 3);
      int cb = (lane & 7) * 16;
      int cbs = cb ^ ((r & 7) << 4);    // inverse-swizzled global source, linear LDS dest
      gload16((const char*)(xf + (size_t)(m0 + r) * 1024 + k0) + cbs, (char*)sA + chunk * 1024);
      gload16((const char*)(wf + (size_t)(c0 + r) * 1024 + k0) + cbs, (char*)sB + chunk * 1024);
    }
    asm volatile("s_waitcnt vmcnt(0)" ::: "memory");
    __syncthreads();

    for (int ki = 0; ki < 2; ++ki) {
      const int colb = (ki * 32 + (lane >> 4) * 8) * 2;
      half8 a[4], bfr[4];
      for (int mi = 0; mi < 4; ++mi)
        a[mi] = lds8h(sA, wm * 64 + mi * 16 + (lane & 15), colb);
      for (int ni = 0; ni < 4; ++ni)
        bfr[ni] = lds8h(sB, wn * 64 + ni * 16 + (lane & 15), colb);
      for (int mi = 0; mi < 4; ++mi)
        for (int ni = 0; ni < 4; ++ni)
          acc[mi][ni] = MFMA16(a[mi], bfr[ni], acc[mi][ni]);
    }
    __syncthreads();
  }

  // epilogue: bias + fragment-layout stores (fp16)
  const int g = lane >> 4, cl = lane & 15;
  const int b = m0 >> 11;
  const int n0t = (m0 & 2047) >> 6;
  const int t = n0t + wm;                 // 64-row tile index within the sequence
  const bool isV = (ct >= 16);
  if (!isV) {
    for (int ni = 0; ni < 4; ++ni) {
      const int c = c0 + wn * 64 + ni * 16 + cl;
      const float bv = bias[c];
      f16* d = (c < 1024) ? qf : kf;
      const int p = c & 63, h = (c & 1023) >> 6;
      const int kki = p >> 5, lhi = (p >> 3) & 3, e = p & 7;
      for (int mi = 0; mi < 4; ++mi) {
        // A/B-operand layout: row-in-tile = mi-slot*16 + lane_lo, elems along p
        size_t base = (((size_t)(b * 16 + h) * 32 + t) * 8 + (size_t)kki * 4 + mi) * 512
                      + (size_t)lhi * 128 + e;
        for (int i = 0; i < 4; ++i)
          d[base + (size_t)(g * 4 + i) * 8] = (f16)(acc[mi][ni][i] + bv);
      }
    }
  } else {
    for (int ni = 0; ni < 4; ++ni) {
      const int c = c0 + wn * 64 + ni * 16 + cl;
      const float bv = bias[c];
      const int cv = c - 2048, h = cv >> 6, p = cv & 63;
      const int niv = p >> 4, lane_lo = p & 15;
      for (int mi = 0; mi < 4; ++mi) {
        const int kki = mi >> 1;
        for (int i = 0; i < 4; ++i) {
          // B-operand layout for PV: row = d (p), elems along kv
          const int lhi = (mi & 1) * 2 + (g >> 1);
          const int e = (g & 1) * 4 + i;
          size_t a = (((size_t)(b * 16 + h) * 32 + t) * 8 + (size_t)kki * 4 + niv) * 512
                     + (size_t)(lhi * 16 + lane_lo) * 8 + e;
          vf[a] = (f16)(acc[mi][ni][i] + bv);
        }
      }
    }
  }
}

// ---------------- flash attention (fp16, swapped-operand softmax) ----------------
// Grid 1024: xcd=bid&7, bh=xcd*8+(li>>4), qt=li&15; 4 waves x 32 q-rows.
// Swapped QK^T: S^T = K.Q^T -> col = q = lane&15, row = kv; row softmax is in-register
// trees + 2 shfls. PV swapped too: O^T = V^T.P^T. No __syncthreads anywhere.
__global__ __launch_bounds__(256, 4) void attn_kernel(
    const f16* __restrict__ qf, const f16* __restrict__ kf,
    const f16* __restrict__ vf, float* __restrict__ out) {
  __shared__ __align__(16) f16 pbuf[4][32 * 72];

  const int tid = threadIdx.x, lane = tid & 63, w = tid >> 6;
  const int bid = blockIdx.x;
  const int xcd = bid & 7, li = bid >> 3;
  const int bh = xcd * 8 + (li >> 4);
  const int qt = li & 15;
  const int g = lane >> 4, q = lane & 15;
  const size_t bhbase = (size_t)bh * 32 * 4096;   // per t: 2ki*4ni*512 = 4096 f16

  // Q fragments — used as B-operand (same per-lane layout as A)
  half8 qfr[2][2];
  for (int mi = 0; mi < 2; ++mi) {
    int idx = 2 * w + mi;
    int t = qt * 2 + (idx >> 2), nni = idx & 3;
    for (int ki = 0; ki < 2; ++ki) {
      size_t a = bhbase + (((size_t)t * 2 + ki) * 4 + nni) * 512 + (size_t)lane * 8;
      qfr[mi][ki] = *(const half8*)(qf + a);
    }
  }

  f32x4 oaccT[2][4] = {};                 // [mi][d-block]: col=q, row=d
  float mrow[2], lrow[2];
  for (int mi = 0; mi < 2; ++mi) { mrow[mi] = -3.0e38f; lrow[mi] = 0.f; }

  for (int t = 0; t < 32; ++t) {
    const size_t tb = bhbase + (size_t)t * 4096;

    // S^T = K Q^T ; K fragments as A-operand, straight from global (L2-resident)
    f32x4 sacc[2][4] = {};                // [mi][kv-block]: col=q, row=kv
    for (int ki = 0; ki < 2; ++ki) {
      half8 khf[4];
      for (int ni = 0; ni < 4; ++ni)
        khf[ni] = *(const half8*)(kf + tb + (((size_t)ki * 4 + ni) * 64 + lane) * 8);
      for (int mi = 0; mi < 2; ++mi)
        for (int ni = 0; ni < 4; ++ni)
          sacc[mi][ni] = MFMA16(khf[ni], qfr[mi][ki], sacc[mi][ni]);
    }

    // issue V fragment loads; latency hides under softmax
    half8 vfr[2][4];
    for (int ki = 0; ki < 2; ++ki)
      for (int ni = 0; ni < 4; ++ni)
        vfr[ki][ni] = *(const half8*)(vf + tb + (((size_t)ki * 4 + ni) * 64 + lane) * 8);

    // softmax: per mi, each lane owns q-row = lane&15; 16 kv values in-register
    for (int mi = 0; mi < 2; ++mi) {
      float a0 = fmaxf(fmaxf(sacc[mi][0][0], sacc[mi][0][1]), fmaxf(sacc[mi][0][2], sacc[mi][0][3]));
      float a1 = fmaxf(fmaxf(sacc[mi][1][0], sacc[mi][1][1]), fmaxf(sacc[mi][1][2], sacc[mi][1][3]));
      float a2 = fmaxf(fmaxf(sacc[mi][2][0], sacc[mi][2][1]), fmaxf(sacc[mi][2][2], sacc[mi][2][3]));
      float a3 = fmaxf(fmaxf(sacc[mi][3][0], sacc[mi][3][1]), fmaxf(sacc[mi][3][2], sacc[mi][3][3]));
      float mx = fmaxf(fmaxf(a0, a1), fmaxf(a2, a3));
      mx = fmaxf(mx, __shfl_xor(mx, 16));
      mx = fmaxf(mx, __shfl_xor(mx, 32));
      float mnew = fmaxf(mrow[mi], mx);
      float corr = __expf(mrow[mi] - mnew);
      mrow[mi] = mnew;
      float rs = 0.f;
      const int prow = mi * 16 + q;
      for (int ni = 0; ni < 4; ++ni) {
        float p0 = __expf(sacc[mi][ni][0] - mnew);
        float p1 = __expf(sacc[mi][ni][1] - mnew);
        float p2 = __expf(sacc[mi][ni][2] - mnew);
        float p3 = __expf(sacc[mi][ni][3] - mnew);
        rs += (p0 + p1) + (p2 + p3);
        half4 pk;
        pk.x = (f16)p0; pk.y = (f16)p1; pk.z = (f16)p2; pk.w = (f16)p3;
        *(half4*)&pbuf[w][prow * 72 + ni * 16 + g * 4] = pk;
      }
      rs += __shfl_xor(rs, 16);
      rs += __shfl_xor(rs, 32);
      lrow[mi] = lrow[mi] * corr + rs;
      for (int ni = 0; ni < 4; ++ni)
        for (int i = 0; i < 4; ++i) oaccT[mi][ni][i] *= corr;
    }

    // O^T += V^T P^T  (A = vf fragment rows=d; B = P rows=q from per-wave pbuf)
    for (int ki = 0; ki < 2; ++ki) {
      half8 pf[2];
      for (int mi = 0; mi < 2; ++mi)
        pf[mi] = *(const half8*)&pbuf[w][(mi * 16 + q) * 72 + ki * 32 + g * 8];
      for (int ni = 0; ni < 4; ++ni)
        for (int mi = 0; mi < 2; ++mi)
          oaccT[mi][ni] = MFMA16(vfr[ki][ni], pf[mi], oaccT[mi][ni]);
    }
  }

  // epilogue: O^T/l -> out (faithful (B,H,N,pd) flat, fp32). col=q, row=d.
  for (int mi = 0; mi < 2; ++mi) {
    float inv = 1.f / lrow[mi];
    int grow = qt * 128 + w * 32 + mi * 16 + q;
    size_t obase = ((size_t)bh * 2048 + grow) * 64;
    for (int ni = 0; ni < 4; ++ni)
      for (int i = 0; i < 4; ++i)
        out[obase + ni * 16 + g * 4 + i] = oaccT[mi][ni][i] * inv;
  }
}

extern "C" void kernel_launch(void* const* d_in, const int* in_sizes, int n_in,
                              void* d_out, int out_size, void* d_ws, size_t ws_size,
                              hipStream_t stream) {
  (void)in_sizes; (void)n_in; (void)out_size; (void)ws_size;
  const float* x = (const float*)d_in[0];
  const float* Wqkv = (const float*)d_in[1];
  const float* bqkv = (const float*)d_in[2];
  float* out = (float*)d_out;

  f16* xf = (f16*)d_ws;                  // [8192][1024]
  f16* wf = xf + 8388608;                // [3072][1024]
  f16* qf = wf + 3145728;                // fragment layouts: [bh][t][ki][ni][lane][8]
  f16* kf = qf + 8388608;
  f16* vf = kf + 8388608;
  // total ws use: ~74 MB (was 130 MB)

  cvt_kernel<<<2048, 256, 0, stream>>>(x, xf, 8388608 / 4);
  cvt_kernel<<<768, 256, 0, stream>>>(Wqkv, wf, 3145728 / 4);
  gemm_qkv<<<1536, 256, 0, stream>>>(xf, wf, bqkv, qf, kf, vf);
  attn_kernel<<<1024, 256, 0, stream>>>(qf, kf, vf, out);
}